// Round 6
// baseline (222.808 us; speedup 1.0000x reference)
//
#include <hip/hip_runtime.h>
#include <hip/hip_bf16.h>
#include <math.h>

// Problem constants
#define Bb   4
#define Cc   128
#define Nn   4096          // 64*64 spatial
#define BN   (Bb * Nn)
#define HP   0.1f
#define EPSN 1e-10f
#define EPSM 0.001f

typedef __attribute__((ext_vector_type(8))) short short8;  // 8 bf16 = 4 VGPRs
typedef __attribute__((ext_vector_type(4))) float f32x4;   // MFMA accumulator

// Workspace layout (float offsets)
#define OFF_MEAN 0                 // [B*C]    = 512   (atomicAdd -> zeroed)
#define OFF_ACC  512               // [B]      = 4     (atomicAdd -> zeroed)
#define OFF_PMAX 1024              // [4][B*N] = 65536 (fully overwritten)
#define OFF_SSP  66560             // [4][B*N] = 65536 (fully overwritten)
#define OFF_FXN  132096            // bf16 [B*N*C] = 1048576 floats
#define OFF_FYN  1180672           // bf16 [B*N*C]

// ---------------------------------------------------------------------------
// Kernel 1: per-(b,c) sums of feature_y over spatial dim (atomicAdd partials)
__global__ void k_mean(const float* __restrict__ fy, float* __restrict__ mean)
{
    int b = blockIdx.x >> 5;
    int chunk = blockIdx.x & 31;
    int c = threadIdx.x;           // 128 threads, one per channel
    const float* p = fy + ((size_t)b * Nn + (size_t)chunk * 128) * Cc + c;
    float s = 0.f;
    for (int n = 0; n < 128; ++n) s += p[(size_t)n * Cc];
    atomicAdd(&mean[b * Cc + c], s);
}

// ---------------------------------------------------------------------------
// Kernel 2: center by spatial mean of y, L2-normalize each (b,n) vector over C,
// emit bf16. 256 threads = 4 waves, one wave per (b,n) row.
__global__ void k_norm(const float* __restrict__ fx, const float* __restrict__ fy,
                       const float* __restrict__ mean,
                       __hip_bfloat16* __restrict__ fxn, __hip_bfloat16* __restrict__ fyn)
{
    int bn = blockIdx.x * 4 + (threadIdx.x >> 6);   // 0 .. B*N-1
    int b = bn >> 12;
    int l = threadIdx.x & 63;
    const float* px = fx + (size_t)bn * Cc;
    const float* py = fy + (size_t)bn * Cc;
    const float* mp = mean + b * Cc;

    float m0 = mp[l]      * (1.f / Nn);
    float m1 = mp[l + 64] * (1.f / Nn);
    float x0 = px[l] - m0, x1 = px[l + 64] - m1;
    float y0 = py[l] - m0, y1 = py[l + 64] - m1;
    float sx = x0 * x0 + x1 * x1;
    float sy = y0 * y0 + y1 * y1;
    #pragma unroll
    for (int o = 32; o > 0; o >>= 1) {
        sx += __shfl_xor(sx, o);
        sy += __shfl_xor(sy, o);
    }
    float ix = 1.f / (sqrtf(sx) + EPSN);
    float iy = 1.f / (sqrtf(sy) + EPSN);
    fxn[(size_t)bn * Cc + l]      = __float2bfloat16(x0 * ix);
    fxn[(size_t)bn * Cc + l + 64] = __float2bfloat16(x1 * ix);
    fyn[(size_t)bn * Cc + l]      = __float2bfloat16(y0 * iy);
    fyn[(size_t)bn * Cc + l + 64] = __float2bfloat16(y1 * iy);
}

// ---------------------------------------------------------------------------
// MFMA core: per batch, S = X · Y^T  (M=N=4096, K=C=128).
// Block = 128-row strip of A (staged once, fragments CACHED IN REGS) x
// 8 m-tiles of B (straight-line unrolled, register-prefetched, single buffer).
// LDS XOR-swizzle: chunk16 c of row r at slot c^(r&15): staging writes and
// frag reads both 2-way bank-aliased = free (m136).
// PASS 1: per-row running max of dot -> pmax[my][b*N+row]
// PASS 2: inline ctv from pmax, per-row sum exp(fma(dot,c1,c0)) -> ssp[my][...]
// Anti-spill discipline (r3-r5 lesson: loop-carried arrays across barriers
// get scratch-lowered -> 80-140 MB HBM writes): prefetch as 8 NAMED float4,
// everything constant-indexed, mt fully unrolled.
#define LOAD_B(t) do { size_t gb_ = mbase + (size_t)(t) * 2048 + go;            \
    p0 = gB4[gb_];        p1 = gB4[gb_ + 256];  p2 = gB4[gb_ + 512];            \
    p3 = gB4[gb_ + 768];  p4 = gB4[gb_ + 1024]; p5 = gB4[gb_ + 1280];           \
    p6 = gB4[gb_ + 1536]; p7 = gB4[gb_ + 1792]; } while (0)

#define COMMIT_B() do {                                                         \
    *(float4*)&sB[lo]         = p0; *(float4*)&sB[lo + 2048]  = p1;             \
    *(float4*)&sB[lo + 4096]  = p2; *(float4*)&sB[lo + 6144]  = p3;             \
    *(float4*)&sB[lo + 8192]  = p4; *(float4*)&sB[lo + 10240] = p5;             \
    *(float4*)&sB[lo + 12288] = p6; *(float4*)&sB[lo + 14336] = p7; } while (0)

template <int PASS>
__global__ __launch_bounds__(256, 1) void k_gemm(
    const ushort* __restrict__ fxn, const ushort* __restrict__ fyn,
    float* __restrict__ pmax, float* __restrict__ ssp)
{
    __shared__ ushort sA[128 * 128];
    __shared__ ushort sB[128 * 128];
    __shared__ float  sred[128 * 2];
    __shared__ float  sctv[128 * 2];

    const int tid  = threadIdx.x;
    const int lane = tid & 63;
    const int w    = tid >> 6;
    const int n0   = blockIdx.x * 128;
    const int my   = blockIdx.y;          // 0..3 -> m-range my*1024..+1023
    const int b    = blockIdx.z;

    const float4* gA4 = (const float4*)(fxn + (size_t)b * Nn * Cc);
    const float4* gB4 = (const float4*)(fyn + (size_t)b * Nn * Cc);

    // PASS 2: reduce pmax partials -> affine exp coefficients, in LDS.
    // arg(dot) = (dmin-(1-dot))*t = dot*t + (d-1)*t with d=1-maxdot, t=1/(HP*(d+eps))
    if (PASS == 2 && tid < 128) {
        int row = b * Nn + n0 + tid;
        float g = pmax[row];
        #pragma unroll
        for (int z = 1; z < 4; ++z) g = fmaxf(g, pmax[(size_t)z * BN + row]);
        float d = 1.f - g;
        float t = 1.f / (HP * (d + EPSM));
        ((float2*)sctv)[tid] = (float2){(d - 1.f) * t, t};
    }

    // Staging geometry: thread covers chunk16 s of rows r0+16*it; XOR slot
    // sx = s^(r&15) = s^(r0&15) is constant across it.
    const int r0 = tid >> 4, sch = tid & 15;
    const int sxs = sch ^ (r0 & 15);
    const int go = r0 * 16 + sch;          // global float4 index base in tile
    const int lo = r0 * 128 + sxs * 8;     // LDS ushort offset base

    // Stage A strip once.
    #pragma unroll
    for (int it = 0; it < 8; ++it)
        *(float4*)&sA[lo + 2048 * it] = gA4[(size_t)n0 * 16 + go + 256 * it];

    const size_t mbase = (size_t)my * 1024 * 16;   // float4 idx of m-strip
    float4 p0, p1, p2, p3, p4, p5, p6, p7;
    LOAD_B(0);
    COMMIT_B();
    LOAD_B(1);
    __syncthreads();    // sA, sB(tile0), sctv all visible

    const int l15 = lane & 15, q = lane >> 4;
    const int wy = w >> 1, wx = w & 1;     // wave's 64x64 quadrant

    // Cache A fragments in registers for the whole block (reused by 8 m-tiles).
    short8 af[4][4];
    #pragma unroll
    for (int kt = 0; kt < 4; ++kt)
        #pragma unroll
        for (int i = 0; i < 4; ++i)
            af[kt][i] = *(const short8*)
                &sA[(wy * 64 + i * 16 + l15) * 128 + ((kt * 4 + q) ^ l15) * 8];

    f32x4 fld[4];                          // PASS1: running max; PASS2: exp-sum
    #pragma unroll
    for (int i = 0; i < 4; ++i)
        fld[i] = (PASS == 1) ? (f32x4){-1e30f, -1e30f, -1e30f, -1e30f}
                             : (f32x4){0.f, 0.f, 0.f, 0.f};

    #pragma unroll
    for (int mt = 0; mt < 8; ++mt) {
        // Compute on sB (holds tile mt); pb holds tile mt+1.
        f32x4 acc[4][4];
        #pragma unroll
        for (int i = 0; i < 4; ++i)
            #pragma unroll
            for (int j = 0; j < 4; ++j)
                acc[i][j] = (f32x4){0.f, 0.f, 0.f, 0.f};

        #pragma unroll
        for (int kt = 0; kt < 4; ++kt) {
            short8 bb[4];
            const int sw = ((kt * 4 + q) ^ l15) * 8;
            #pragma unroll
            for (int j = 0; j < 4; ++j)
                bb[j] = *(const short8*)&sB[(wx * 64 + j * 16 + l15) * 128 + sw];
            #pragma unroll
            for (int i = 0; i < 4; ++i)
                #pragma unroll
                for (int j = 0; j < 4; ++j)
                    acc[i][j] = __builtin_amdgcn_mfma_f32_16x16x32_bf16(
                        af[kt][i], bb[j], acc[i][j], 0, 0, 0);
        }

        // Fold m-tile into running per-row state.
        // C/D layout: col = lane&15, row = (lane>>4)*4 + reg  [m89-verified]
        #pragma unroll
        for (int i = 0; i < 4; ++i)
            #pragma unroll
            for (int r = 0; r < 4; ++r) {
                if (PASS == 1) {
                    float v = acc[i][0][r];
                    #pragma unroll
                    for (int j = 1; j < 4; ++j) v = fmaxf(v, acc[i][j][r]);
                    fld[i][r] = fmaxf(fld[i][r], v);
                } else {
                    int row = wy * 64 + i * 16 + q * 4 + r;
                    float2 cc = ((const float2*)sctv)[row];   // {c0, c1}
                    float sum = 0.f;
                    #pragma unroll
                    for (int j = 0; j < 4; ++j)
                        sum += __expf(fmaf(acc[i][j][r], cc.y, cc.x)); // arg <= ~0
                    fld[i][r] += sum;
                }
            }

        __syncthreads();               // all waves done reading sB(tile mt)
        if (mt < 7) {
            COMMIT_B();                // sB <- tile mt+1
            if (mt < 6) LOAD_B(mt + 2);
            __syncthreads();           // sB(tile mt+1) visible
        }
    }

    // Per-row reduction across 16 columns (l15 group) and the wx wave pair.
    #pragma unroll
    for (int i = 0; i < 4; ++i)
        #pragma unroll
        for (int r = 0; r < 4; ++r) {
            float v = fld[i][r];
            if (PASS == 1) {
                #pragma unroll
                for (int o = 1; o < 16; o <<= 1) v = fmaxf(v, __shfl_xor(v, o));
            } else {
                #pragma unroll
                for (int o = 1; o < 16; o <<= 1) v += __shfl_xor(v, o);
            }
            if (l15 == 0) sred[(wy * 64 + i * 16 + q * 4 + r) * 2 + wx] = v;
        }
    __syncthreads();
    if (tid < 128) {
        float v = (PASS == 1) ? fmaxf(sred[tid * 2], sred[tid * 2 + 1])
                              : (sred[tid * 2] + sred[tid * 2 + 1]);
        float* dst = (PASS == 1) ? pmax : ssp;
        dst[(size_t)my * BN + b * Nn + n0 + tid] = v;
    }
}

// ---------------------------------------------------------------------------
// Stage 1 of final reduction: per-row 1/s, block-sum, atomicAdd per batch.
__global__ void k_partial(const float* __restrict__ ssp, float* __restrict__ acc)
{
    int i = blockIdx.x * 256 + threadIdx.x;   // 0 .. B*N-1 (block spans one batch)
    float t = 0.f;
    #pragma unroll
    for (int z = 0; z < 4; ++z) t += ssp[(size_t)z * BN + i];
    float s = 1.f / t;
    #pragma unroll
    for (int o = 32; o > 0; o >>= 1) s += __shfl_xor(s, o);
    __shared__ float red[4];
    if ((threadIdx.x & 63) == 0) red[threadIdx.x >> 6] = s;
    __syncthreads();
    if (threadIdx.x == 0)
        atomicAdd(&acc[i >> 12], red[0] + red[1] + red[2] + red[3]);
}

__global__ void k_out(const float* __restrict__ acc, float* __restrict__ out)
{
    int b = threadIdx.x;
    if (b < Bb) out[b] = -logf(acc[b] * (1.f / Nn));
}

// ---------------------------------------------------------------------------
extern "C" void kernel_launch(void* const* d_in, const int* in_sizes, int n_in,
                              void* d_out, int out_size, void* d_ws, size_t ws_size,
                              hipStream_t stream)
{
    const float* fx = (const float*)d_in[0];
    const float* fy = (const float*)d_in[1];
    float* out = (float*)d_out;
    float* ws  = (float*)d_ws;

    float* mean = ws + OFF_MEAN;
    float* acc  = ws + OFF_ACC;
    float* pmax = ws + OFF_PMAX;
    float* ssp  = ws + OFF_SSP;
    __hip_bfloat16* fxn = (__hip_bfloat16*)(ws + OFF_FXN);
    __hip_bfloat16* fyn = (__hip_bfloat16*)(ws + OFF_FYN);

    // zero the atomicAdd accumulators (mean @0..511, acc @512..515)
    hipMemsetAsync(ws, 0, 516 * sizeof(float), stream);

    k_mean<<<dim3(Bb * 32), dim3(128), 0, stream>>>(fy, mean);
    k_norm<<<dim3(Bb * Nn / 4), dim3(256), 0, stream>>>(fx, fy, mean, fxn, fyn);

    dim3 gg(32, 4, Bb);   // 512 blocks = 2/CU, 8 m-tiles each
    k_gemm<1><<<gg, dim3(256), 0, stream>>>((const ushort*)fxn, (const ushort*)fyn,
                                            pmax, nullptr);
    k_gemm<2><<<gg, dim3(256), 0, stream>>>((const ushort*)fxn, (const ushort*)fyn,
                                            pmax, ssp);
    k_partial<<<dim3(BN / 256), dim3(256), 0, stream>>>(ssp, acc);
    k_out<<<dim3(1), dim3(64), 0, stream>>>(acc, out);
}

// Round 7
// 158.546 us; speedup vs baseline: 1.4053x; 1.4053x over previous
//
#include <hip/hip_runtime.h>
#include <hip/hip_bf16.h>
#include <math.h>

// Problem constants
#define Bb   4
#define Cc   128
#define Nn   4096          // 64*64 spatial
#define BN   (Bb * Nn)
#define HP   0.1f
#define EPSN 1e-10f
#define EPSM 0.001f

typedef __attribute__((ext_vector_type(8))) short short8;  // 8 bf16 = 4 VGPRs
typedef __attribute__((ext_vector_type(4))) float f32x4;   // MFMA accumulator

// Workspace layout (float offsets)
#define OFF_MEAN 0                 // [B*C]     = 512    (atomicAdd -> zeroed)
#define OFF_ACC  512               // [B]       = 4      (atomicAdd -> zeroed)
#define OFF_PMAX 1024              // [32][B*N] = 524288 (fully overwritten)
#define OFF_SSP  525312            // [32][B*N] = 524288 (fully overwritten)
#define OFF_FXN  1049600           // bf16 [B*N*C] = 1048576 floats
#define OFF_FYN  2098176           // bf16 [B*N*C]

// async global -> LDS, 16B per lane; LDS dest = wave-uniform base + lane*16
__device__ __forceinline__ void gload_lds16(const void* g, void* l)
{
    __builtin_amdgcn_global_load_lds(
        (const __attribute__((address_space(1))) unsigned int*)g,
        (__attribute__((address_space(3))) unsigned int*)l, 16, 0, 0);
}

// ---------------------------------------------------------------------------
// Kernel 1: per-(b,c) sums of feature_y over spatial dim (atomicAdd partials)
__global__ void k_mean(const float* __restrict__ fy, float* __restrict__ mean)
{
    int b = blockIdx.x >> 5;
    int chunk = blockIdx.x & 31;
    int c = threadIdx.x;           // 128 threads, one per channel
    const float* p = fy + ((size_t)b * Nn + (size_t)chunk * 128) * Cc + c;
    float s = 0.f;
    for (int n = 0; n < 128; ++n) s += p[(size_t)n * Cc];
    atomicAdd(&mean[b * Cc + c], s);
}

// ---------------------------------------------------------------------------
// Kernel 2: center by spatial mean of y, L2-normalize each (b,n) vector over C,
// emit bf16. 256 threads = 4 waves, one wave per (b,n) row.
__global__ void k_norm(const float* __restrict__ fx, const float* __restrict__ fy,
                       const float* __restrict__ mean,
                       __hip_bfloat16* __restrict__ fxn, __hip_bfloat16* __restrict__ fyn)
{
    int bn = blockIdx.x * 4 + (threadIdx.x >> 6);   // 0 .. B*N-1
    int b = bn >> 12;
    int l = threadIdx.x & 63;
    const float* px = fx + (size_t)bn * Cc;
    const float* py = fy + (size_t)bn * Cc;
    const float* mp = mean + b * Cc;

    float m0 = mp[l]      * (1.f / Nn);
    float m1 = mp[l + 64] * (1.f / Nn);
    float x0 = px[l] - m0, x1 = px[l + 64] - m1;
    float y0 = py[l] - m0, y1 = py[l + 64] - m1;
    float sx = x0 * x0 + x1 * x1;
    float sy = y0 * y0 + y1 * y1;
    #pragma unroll
    for (int o = 32; o > 0; o >>= 1) {
        sx += __shfl_xor(sx, o);
        sy += __shfl_xor(sy, o);
    }
    float ix = 1.f / (sqrtf(sx) + EPSN);
    float iy = 1.f / (sqrtf(sy) + EPSN);
    fxn[(size_t)bn * Cc + l]      = __float2bfloat16(x0 * ix);
    fxn[(size_t)bn * Cc + l + 64] = __float2bfloat16(x1 * ix);
    fyn[(size_t)bn * Cc + l]      = __float2bfloat16(y0 * iy);
    fyn[(size_t)bn * Cc + l + 64] = __float2bfloat16(y1 * iy);
}

// ---------------------------------------------------------------------------
// MFMA core: per batch, S = X · Y^T  (M=N=4096, K=C=128).
// Block = 128-row strip of A (staged ONCE via async global_load_lds) x
// 4 m-tiles of B (mt-loop, single sB buffer, async staging, 2 barriers/mt).
// CRITICAL (rounds 2 vs 3-6): each mt iteration runs the FULL epilogue
// (shuffle-reduce + partial store), so acc is born and dies inside one
// iteration with zero loop-carried vector state. That is the only shape the
// compiler maps acc to AGPRs (r2: VGPR=88, WRITE=2MB); any cross-iteration
// fold/prefetch state forces acc into VGPRs and scratch-spills 77-170 MB.
// LDS XOR-swizzle: chunk16 c of row r at slot c^(r&15) -> async staging is
// lane-linear, frag ds_read_b128 2-way bank-aliased = free (m136).
// PASS 1: per-row per-mtile max of dot -> pmax[my*4+mt][b*N+row]
// PASS 2: prologue reduces pmax -> affine exp coeffs in LDS;
//         per-row per-mtile sum exp(fma(dot,c1,c0)) -> ssp[my*4+mt][...]
template <int PASS>
__global__ __launch_bounds__(256, 2) void k_gemm(
    const ushort* __restrict__ fxn, const ushort* __restrict__ fyn,
    float* __restrict__ pmax, float* __restrict__ ssp)
{
    __shared__ ushort sA[128 * 128];
    __shared__ ushort sB[128 * 128];
    __shared__ float  sred[256];
    __shared__ float  sctv[256];

    const int tid  = threadIdx.x;
    const int lane = tid & 63;
    const int w    = tid >> 6;
    const int n0   = blockIdx.x * 128;
    const int my   = blockIdx.y;          // 0..7 -> m-tiles my*4 .. my*4+3
    const int b    = blockIdx.z;

    const ushort* gA = fxn + (size_t)b * Nn * Cc;
    const ushort* gB = fyn + (size_t)b * Nn * Cc;

    // PASS 2 prologue: 32 max-partials -> {c0,c1}: arg(dot) = dot*t + (d-1)*t,
    // d = 1 - maxdot, t = 1/(HP*(d+eps)).
    if (PASS == 2 && tid < 128) {
        int row = b * Nn + n0 + tid;
        float g = -1e30f;
        #pragma unroll
        for (int z = 0; z < 32; ++z) g = fmaxf(g, pmax[(size_t)z * BN + row]);
        float d = 1.f - g;
        float t = 1.f / (HP * (d + EPSM));
        ((float2*)sctv)[tid] = (float2){(d - 1.f) * t, t};
    }

    // Stage A strip once (async DMA, no VGPR roundtrip).
    #pragma unroll
    for (int inst = 0; inst < 8; ++inst) {
        int L0 = w * 512 + inst * 64;
        int L  = L0 + lane;
        int r = L >> 4, s = L & 15;
        int c = s ^ (r & 15);
        gload_lds16(gA + (size_t)(n0 + r) * Cc + c * 8, &sA[L0 * 8]);
    }

    const int l15 = lane & 15, q = lane >> 4;
    const int wy = w >> 1, wx = w & 1;     // wave's 64x64 quadrant

    #pragma unroll 1
    for (int mt = 0; mt < 4; ++mt) {
        const int m0 = (my * 4 + mt) * 128;
        // Stage B tile (async DMA).
        #pragma unroll
        for (int inst = 0; inst < 8; ++inst) {
            int L0 = w * 512 + inst * 64;
            int L  = L0 + lane;
            int r = L >> 4, s = L & 15;
            int c = s ^ (r & 15);
            gload_lds16(gB + (size_t)(m0 + r) * Cc + c * 8, &sB[L0 * 8]);
        }
        __syncthreads();   // vmcnt drained: sA (first iter) + sB staged; sctv visible

        f32x4 acc[4][4];
        #pragma unroll
        for (int i = 0; i < 4; ++i)
            #pragma unroll
            for (int j = 0; j < 4; ++j)
                acc[i][j] = (f32x4){0.f, 0.f, 0.f, 0.f};

        #pragma unroll
        for (int kt = 0; kt < 4; ++kt) {
            short8 a[4], bb[4];
            const int sw = ((kt * 4 + q) ^ l15) * 8;   // swizzled chunk offset
            #pragma unroll
            for (int i = 0; i < 4; ++i)
                a[i] = *(const short8*)&sA[(wy * 64 + i * 16 + l15) * 128 + sw];
            #pragma unroll
            for (int j = 0; j < 4; ++j)
                bb[j] = *(const short8*)&sB[(wx * 64 + j * 16 + l15) * 128 + sw];
            #pragma unroll
            for (int i = 0; i < 4; ++i)
                #pragma unroll
                for (int j = 0; j < 4; ++j)
                    acc[i][j] = __builtin_amdgcn_mfma_f32_16x16x32_bf16(
                        a[i], bb[j], acc[i][j], 0, 0, 0);
        }

        // Full epilogue for this m-tile (acc dies here -> stays in AGPRs).
        // C/D layout: col = lane&15, row = (lane>>4)*4 + reg  [m89-verified]
        #pragma unroll
        for (int i = 0; i < 4; ++i)
            #pragma unroll
            for (int r = 0; r < 4; ++r) {
                float v;
                if (PASS == 1) {
                    v = acc[i][0][r];
                    #pragma unroll
                    for (int j = 1; j < 4; ++j) v = fmaxf(v, acc[i][j][r]);
                    #pragma unroll
                    for (int o = 1; o < 16; o <<= 1) v = fmaxf(v, __shfl_xor(v, o));
                } else {
                    int row = wy * 64 + i * 16 + q * 4 + r;
                    float2 cc = ((const float2*)sctv)[row];   // {c0, c1}
                    v = 0.f;
                    #pragma unroll
                    for (int j = 0; j < 4; ++j)
                        v += __expf(fmaf(acc[i][j][r], cc.y, cc.x));  // arg <= ~0
                    #pragma unroll
                    for (int o = 1; o < 16; o <<= 1) v += __shfl_xor(v, o);
                }
                if (l15 == 0) sred[(wy * 64 + i * 16 + q * 4 + r) * 2 + wx] = v;
            }
        __syncthreads();   // sred complete; also fences sB reads before restage
        if (tid < 128) {
            float v = (PASS == 1) ? fmaxf(sred[tid * 2], sred[tid * 2 + 1])
                                  : (sred[tid * 2] + sred[tid * 2 + 1]);
            float* dst = (PASS == 1) ? pmax : ssp;
            dst[(size_t)(my * 4 + mt) * BN + b * Nn + n0 + tid] = v;
        }
        // next iteration's staging + barrier protect sred/sB reuse
    }
}

// ---------------------------------------------------------------------------
// Stage 1 of final reduction: per-row 1/s, block-sum, atomicAdd per batch.
__global__ void k_partial(const float* __restrict__ ssp, float* __restrict__ acc)
{
    int i = blockIdx.x * 256 + threadIdx.x;   // 0 .. B*N-1 (block spans one batch)
    float t = 0.f;
    #pragma unroll
    for (int z = 0; z < 32; ++z) t += ssp[(size_t)z * BN + i];
    float s = 1.f / t;
    #pragma unroll
    for (int o = 32; o > 0; o >>= 1) s += __shfl_xor(s, o);
    __shared__ float red[4];
    if ((threadIdx.x & 63) == 0) red[threadIdx.x >> 6] = s;
    __syncthreads();
    if (threadIdx.x == 0)
        atomicAdd(&acc[i >> 12], red[0] + red[1] + red[2] + red[3]);
}

__global__ void k_out(const float* __restrict__ acc, float* __restrict__ out)
{
    int b = threadIdx.x;
    if (b < Bb) out[b] = -logf(acc[b] * (1.f / Nn));
}

// ---------------------------------------------------------------------------
extern "C" void kernel_launch(void* const* d_in, const int* in_sizes, int n_in,
                              void* d_out, int out_size, void* d_ws, size_t ws_size,
                              hipStream_t stream)
{
    const float* fx = (const float*)d_in[0];
    const float* fy = (const float*)d_in[1];
    float* out = (float*)d_out;
    float* ws  = (float*)d_ws;

    float* mean = ws + OFF_MEAN;
    float* acc  = ws + OFF_ACC;
    float* pmax = ws + OFF_PMAX;
    float* ssp  = ws + OFF_SSP;
    __hip_bfloat16* fxn = (__hip_bfloat16*)(ws + OFF_FXN);
    __hip_bfloat16* fyn = (__hip_bfloat16*)(ws + OFF_FYN);

    // zero the atomicAdd accumulators (mean @0..511, acc @512..515)
    hipMemsetAsync(ws, 0, 516 * sizeof(float), stream);

    k_mean<<<dim3(Bb * 32), dim3(128), 0, stream>>>(fy, mean);
    k_norm<<<dim3(Bb * Nn / 4), dim3(256), 0, stream>>>(fx, fy, mean, fxn, fyn);

    dim3 gg(32, 8, Bb);   // 1024 blocks = 2/CU (66 KB LDS), 4 m-tiles each
    k_gemm<1><<<gg, dim3(256), 0, stream>>>((const ushort*)fxn, (const ushort*)fyn,
                                            pmax, nullptr);
    k_gemm<2><<<gg, dim3(256), 0, stream>>>((const ushort*)fxn, (const ushort*)fyn,
                                            pmax, ssp);
    k_partial<<<dim3(BN / 256), dim3(256), 0, stream>>>(ssp, acc);
    k_out<<<dim3(1), dim3(64), 0, stream>>>(acc, out);
}

// Round 8
// 153.553 us; speedup vs baseline: 1.4510x; 1.0325x over previous
//
#include <hip/hip_runtime.h>
#include <hip/hip_bf16.h>
#include <math.h>

// Problem constants
#define Bb   4
#define Cc   128
#define Nn   4096          // 64*64 spatial
#define BN   (Bb * Nn)
#define HP   0.1f
#define EPSN 1e-10f
#define EPSM 0.001f

typedef __attribute__((ext_vector_type(8))) short short8;  // 8 bf16 = 4 VGPRs
typedef __attribute__((ext_vector_type(4))) float f32x4;   // MFMA accumulator

// Workspace layout (float offsets)
#define OFF_MEAN 0                 // [B*C]     = 512    (atomicAdd -> zeroed)
#define OFF_ACC  512               // [B]       = 4      (atomicAdd -> zeroed)
#define OFF_PMAX 1024              // [32][B*N] = 524288 (fully overwritten)
#define OFF_SSP  525312            // [32][B*N] = 524288 (fully overwritten)
#define OFF_FXN  1049600           // bf16 [B*N*C] = 1048576 floats
#define OFF_FYN  2098176           // bf16 [B*N*C]

// async global -> LDS, 16B per lane; LDS dest = wave-uniform base + lane*16
__device__ __forceinline__ void gload_lds16(const void* g, void* l)
{
    __builtin_amdgcn_global_load_lds(
        (const __attribute__((address_space(1))) unsigned int*)g,
        (__attribute__((address_space(3))) unsigned int*)l, 16, 0, 0);
}

// ---------------------------------------------------------------------------
// Kernel 1: per-(b,c) sums of feature_y over spatial dim (atomicAdd partials)
__global__ void k_mean(const float* __restrict__ fy, float* __restrict__ mean)
{
    int b = blockIdx.x >> 5;
    int chunk = blockIdx.x & 31;
    int c = threadIdx.x;           // 128 threads, one per channel
    const float* p = fy + ((size_t)b * Nn + (size_t)chunk * 128) * Cc + c;
    float s = 0.f;
    for (int n = 0; n < 128; ++n) s += p[(size_t)n * Cc];
    atomicAdd(&mean[b * Cc + c], s);
}

// ---------------------------------------------------------------------------
// Kernel 2: center by spatial mean of y, L2-normalize each (b,n) vector over C,
// emit bf16. 256 threads = 4 waves, one wave per (b,n) row.
__global__ void k_norm(const float* __restrict__ fx, const float* __restrict__ fy,
                       const float* __restrict__ mean,
                       __hip_bfloat16* __restrict__ fxn, __hip_bfloat16* __restrict__ fyn)
{
    int bn = blockIdx.x * 4 + (threadIdx.x >> 6);   // 0 .. B*N-1
    int b = bn >> 12;
    int l = threadIdx.x & 63;
    const float* px = fx + (size_t)bn * Cc;
    const float* py = fy + (size_t)bn * Cc;
    const float* mp = mean + b * Cc;

    float m0 = mp[l]      * (1.f / Nn);
    float m1 = mp[l + 64] * (1.f / Nn);
    float x0 = px[l] - m0, x1 = px[l + 64] - m1;
    float y0 = py[l] - m0, y1 = py[l + 64] - m1;
    float sx = x0 * x0 + x1 * x1;
    float sy = y0 * y0 + y1 * y1;
    #pragma unroll
    for (int o = 32; o > 0; o >>= 1) {
        sx += __shfl_xor(sx, o);
        sy += __shfl_xor(sy, o);
    }
    float ix = 1.f / (sqrtf(sx) + EPSN);
    float iy = 1.f / (sqrtf(sy) + EPSN);
    fxn[(size_t)bn * Cc + l]      = __float2bfloat16(x0 * ix);
    fxn[(size_t)bn * Cc + l + 64] = __float2bfloat16(x1 * ix);
    fyn[(size_t)bn * Cc + l]      = __float2bfloat16(y0 * iy);
    fyn[(size_t)bn * Cc + l + 64] = __float2bfloat16(y1 * iy);
}

// ---------------------------------------------------------------------------
// MFMA core: per batch, S = X · Y^T  (M=N=4096, K=C=128).
// Block = 128-row strip of A (staged once, async DMA, XOR-swizzled LDS) x
// 2 m-tiles of B. B-FRAGMENTS COME STRAIGHT FROM GLOBAL (dwordx4, L1/L2-hot,
// 2 MB/batch resident) -- no sB, no staging barrier in the mt loop; LDS pipe
// only carries A-frags + the epilogue transpose.
// Epilogue per m-tile (acc born+dies per iteration -> AGPRs; the r2-vs-r3..6
// spill rule): j-reduce in regs, transpose via sred[128][36] (stride 36:
// writes 2-way bank-aliased = free, reads 16B-aligned b128), 128 threads
// reduce 32 slots/row, store partial.
// PASS 1: per-row per-mtile max of dot -> pmax[my*2+mt][b*N+row]
// PASS 2: prologue reduces pmax -> affine exp coeffs in LDS;
//         per-row per-mtile sum exp(fma(dot,c1,c0)) -> ssp[my*2+mt][...]
template <int PASS>
__global__ __launch_bounds__(256, 3) void k_gemm(
    const ushort* __restrict__ fxn, const ushort* __restrict__ fyn,
    float* __restrict__ pmax, float* __restrict__ ssp)
{
    __shared__ ushort sA[128 * 128];    // 32 KB
    __shared__ float  sred[128 * 36];   // 18 KB transpose buffer
    __shared__ float  sctv[256];        // 1 KB {c0,c1} per row

    const int tid  = threadIdx.x;
    const int lane = tid & 63;
    const int w    = tid >> 6;
    const int n0   = blockIdx.x * 128;
    const int my   = blockIdx.y;          // 0..15 -> m-tiles 2my, 2my+1
    const int b    = blockIdx.z;

    const ushort* gA = fxn + (size_t)b * Nn * Cc;
    const ushort* gB = fyn + (size_t)b * Nn * Cc;

    // PASS 2 prologue: 32 max-partials -> {c0,c1}: arg(dot) = dot*t + (d-1)*t,
    // d = 1 - maxdot, t = 1/(HP*(d+eps)).
    if (PASS == 2 && tid < 128) {
        int row = b * Nn + n0 + tid;
        float g = -1e30f;
        #pragma unroll
        for (int z = 0; z < 32; ++z) g = fmaxf(g, pmax[(size_t)z * BN + row]);
        float d = 1.f - g;
        float t = 1.f / (HP * (d + EPSM));
        ((float2*)sctv)[tid] = (float2){(d - 1.f) * t, t};
    }

    // Stage A strip once (async DMA; chunk16 c of row r at slot c^(r&15)).
    #pragma unroll
    for (int inst = 0; inst < 8; ++inst) {
        int L0 = w * 512 + inst * 64;
        int L  = L0 + lane;
        int r = L >> 4, s = L & 15;
        int c = s ^ (r & 15);
        gload_lds16(gA + (size_t)(n0 + r) * Cc + c * 8, &sA[L0 * 8]);
    }
    __syncthreads();   // drains DMA; sA + sctv visible

    const int l15 = lane & 15, q = lane >> 4;
    const int wy = w >> 1, wx = w & 1;     // wave's 64x64 quadrant

    #pragma unroll 1
    for (int mt = 0; mt < 2; ++mt) {
        const int m0 = (my * 2 + mt) * 128;
        // Per-lane B base: row m0 + wx*64 + l15, col chunk q*8.
        const ushort* pB = gB + (size_t)(m0 + wx * 64 + l15) * Cc + q * 8;

        f32x4 acc[4][4];
        #pragma unroll
        for (int i = 0; i < 4; ++i)
            #pragma unroll
            for (int j = 0; j < 4; ++j)
                acc[i][j] = (f32x4){0.f, 0.f, 0.f, 0.f};

        #pragma unroll
        for (int kt = 0; kt < 4; ++kt) {
            short8 a[4], bb[4];
            const int sw = ((kt * 4 + q) ^ l15) * 8;   // swizzled A chunk
            #pragma unroll
            for (int j = 0; j < 4; ++j)
                bb[j] = *(const short8*)(pB + (size_t)j * 16 * Cc + kt * 32);
            #pragma unroll
            for (int i = 0; i < 4; ++i)
                a[i] = *(const short8*)&sA[(wy * 64 + i * 16 + l15) * 128 + sw];
            #pragma unroll
            for (int i = 0; i < 4; ++i)
                #pragma unroll
                for (int j = 0; j < 4; ++j)
                    acc[i][j] = __builtin_amdgcn_mfma_f32_16x16x32_bf16(
                        a[i], bb[j], acc[i][j], 0, 0, 0);
        }

        // Epilogue: j-reduce in regs, transpose through sred, reduce, store.
        // C/D layout: col = lane&15, row = (lane>>4)*4 + reg  [m89-verified]
        #pragma unroll
        for (int i = 0; i < 4; ++i)
            #pragma unroll
            for (int r = 0; r < 4; ++r) {
                int row = wy * 64 + i * 16 + q * 4 + r;
                float v;
                if (PASS == 1) {
                    v = fmaxf(fmaxf(acc[i][0][r], acc[i][1][r]),
                              fmaxf(acc[i][2][r], acc[i][3][r]));
                } else {
                    float2 cc = ((const float2*)sctv)[row];   // {c0, c1}
                    v = __expf(fmaf(acc[i][0][r], cc.y, cc.x))
                      + __expf(fmaf(acc[i][1][r], cc.y, cc.x))
                      + __expf(fmaf(acc[i][2][r], cc.y, cc.x))
                      + __expf(fmaf(acc[i][3][r], cc.y, cc.x));  // args <= ~0
                }
                sred[row * 36 + wx * 16 + l15] = v;
            }
        __syncthreads();   // sred complete
        if (tid < 128) {
            const float4* p = (const float4*)&sred[tid * 36];
            float4 v0 = p[0], v1 = p[1], v2 = p[2], v3 = p[3];
            float4 v4 = p[4], v5 = p[5], v6 = p[6], v7 = p[7];
            float v;
            if (PASS == 1) {
                float4 m01 = (float4){fmaxf(v0.x, v1.x), fmaxf(v0.y, v1.y),
                                      fmaxf(v0.z, v1.z), fmaxf(v0.w, v1.w)};
                float4 m23 = (float4){fmaxf(v2.x, v3.x), fmaxf(v2.y, v3.y),
                                      fmaxf(v2.z, v3.z), fmaxf(v2.w, v3.w)};
                float4 m45 = (float4){fmaxf(v4.x, v5.x), fmaxf(v4.y, v5.y),
                                      fmaxf(v4.z, v5.z), fmaxf(v4.w, v5.w)};
                float4 m67 = (float4){fmaxf(v6.x, v7.x), fmaxf(v6.y, v7.y),
                                      fmaxf(v6.z, v7.z), fmaxf(v6.w, v7.w)};
                float4 ma = (float4){fmaxf(m01.x, m23.x), fmaxf(m01.y, m23.y),
                                     fmaxf(m01.z, m23.z), fmaxf(m01.w, m23.w)};
                float4 mb = (float4){fmaxf(m45.x, m67.x), fmaxf(m45.y, m67.y),
                                     fmaxf(m45.z, m67.z), fmaxf(m45.w, m67.w)};
                v = fmaxf(fmaxf(fmaxf(ma.x, mb.x), fmaxf(ma.y, mb.y)),
                          fmaxf(fmaxf(ma.z, mb.z), fmaxf(ma.w, mb.w)));
            } else {
                float4 s01 = (float4){v0.x + v1.x, v0.y + v1.y,
                                      v0.z + v1.z, v0.w + v1.w};
                float4 s23 = (float4){v2.x + v3.x, v2.y + v3.y,
                                      v2.z + v3.z, v2.w + v3.w};
                float4 s45 = (float4){v4.x + v5.x, v4.y + v5.y,
                                      v4.z + v5.z, v4.w + v5.w};
                float4 s67 = (float4){v6.x + v7.x, v6.y + v7.y,
                                      v6.z + v7.z, v6.w + v7.w};
                v = (s01.x + s23.x) + (s01.y + s23.y)
                  + (s01.z + s23.z) + (s01.w + s23.w)
                  + (s45.x + s67.x) + (s45.y + s67.y)
                  + (s45.z + s67.z) + (s45.w + s67.w);
            }
            float* dst = (PASS == 1) ? pmax : ssp;
            dst[(size_t)(my * 2 + mt) * BN + b * Nn + n0 + tid] = v;
        }
        __syncthreads();   // sred reusable next mt
    }
}

// ---------------------------------------------------------------------------
// Stage 1 of final reduction: per-row 1/s, block-sum, atomicAdd per batch.
__global__ void k_partial(const float* __restrict__ ssp, float* __restrict__ acc)
{
    int i = blockIdx.x * 256 + threadIdx.x;   // 0 .. B*N-1 (block spans one batch)
    float t = 0.f;
    #pragma unroll
    for (int z = 0; z < 32; ++z) t += ssp[(size_t)z * BN + i];
    float s = 1.f / t;
    #pragma unroll
    for (int o = 32; o > 0; o >>= 1) s += __shfl_xor(s, o);
    __shared__ float red[4];
    if ((threadIdx.x & 63) == 0) red[threadIdx.x >> 6] = s;
    __syncthreads();
    if (threadIdx.x == 0)
        atomicAdd(&acc[i >> 12], red[0] + red[1] + red[2] + red[3]);
}

__global__ void k_out(const float* __restrict__ acc, float* __restrict__ out)
{
    int b = threadIdx.x;
    if (b < Bb) out[b] = -logf(acc[b] * (1.f / Nn));
}

// ---------------------------------------------------------------------------
extern "C" void kernel_launch(void* const* d_in, const int* in_sizes, int n_in,
                              void* d_out, int out_size, void* d_ws, size_t ws_size,
                              hipStream_t stream)
{
    const float* fx = (const float*)d_in[0];
    const float* fy = (const float*)d_in[1];
    float* out = (float*)d_out;
    float* ws  = (float*)d_ws;

    float* mean = ws + OFF_MEAN;
    float* acc  = ws + OFF_ACC;
    float* pmax = ws + OFF_PMAX;
    float* ssp  = ws + OFF_SSP;
    __hip_bfloat16* fxn = (__hip_bfloat16*)(ws + OFF_FXN);
    __hip_bfloat16* fyn = (__hip_bfloat16*)(ws + OFF_FYN);

    // zero the atomicAdd accumulators (mean @0..511, acc @512..515)
    hipMemsetAsync(ws, 0, 516 * sizeof(float), stream);

    k_mean<<<dim3(Bb * 32), dim3(128), 0, stream>>>(fy, mean);
    k_norm<<<dim3(Bb * Nn / 4), dim3(256), 0, stream>>>(fx, fy, mean, fxn, fyn);

    dim3 gg(32, 16, Bb);   // 2048 blocks, 2 m-tiles each; ~3 blocks/CU (51 KB LDS)
    k_gemm<1><<<gg, dim3(256), 0, stream>>>((const ushort*)fxn, (const ushort*)fyn,
                                            pmax, nullptr);
    k_gemm<2><<<gg, dim3(256), 0, stream>>>((const ushort*)fxn, (const ushort*)fyn,
                                            pmax, ssp);
    k_partial<<<dim3(BN / 256), dim3(256), 0, stream>>>(ssp, acc);
    k_out<<<dim3(1), dim3(64), 0, stream>>>(acc, out);
}